// Round 1
// baseline (131.362 us; speedup 1.0000x reference)
//
#include <hip/hip_runtime.h>
#include <hip/hip_bf16.h>
#include <math.h>

// Problem constants (from reference)
#define B 8
#define S 512
#define A 4
#define N (S*A)          // 2048 points per batch for the LJ term
#define SIGMA 3.0f
#define HB_R0 2.9f
#define HB_COEF (-12.5f) // -0.5 / 0.2^2
#define EPS 1e-6f

// Workspace layout (floats):
// [0] lj_num  [1] lj_den  [2] hb_num  [3] mask_sum
// [4] motor_num  [5] motor_den
// [8 + b*8 + {0,1,2}] = S1 (sum ca*m, xyz)   [.. +3] = S2 (sum |ca|^2 m)
// [.. +4] = M (sum mask, per batch)

__device__ __forceinline__ float wave_reduce_sum(float v) {
    #pragma unroll
    for (int off = 32; off > 0; off >>= 1) v += __shfl_down(v, off, 64);
    return v;
}

// ---------------- LJ clash term ----------------
// grid: (jt=8, it=8, b=8), block: 256. Each thread owns one i, loops a 256-wide
// j tile staged in LDS (broadcast reads, conflict-free).
__global__ void lj_kernel(const float* __restrict__ coords,
                          const float* __restrict__ mask,
                          float* __restrict__ ws) {
    const int b  = blockIdx.z;
    const int it = blockIdx.y;
    const int jt = blockIdx.x;
    const int tid = threadIdx.x;

    __shared__ float sx[256], sy[256], sz[256], sm[256];
    const float* cb = coords + (size_t)b * N * 3;

    const int j = jt * 256 + tid;
    sx[tid] = cb[j*3 + 0];
    sy[tid] = cb[j*3 + 1];
    sz[tid] = cb[j*3 + 2];
    sm[tid] = mask[b*S + (j >> 2)];
    __syncthreads();

    const int i = it * 256 + tid;
    const float xi = cb[i*3 + 0];
    const float yi = cb[i*3 + 1];
    const float zi = cb[i*3 + 2];
    const float fmi = mask[b*S + (i >> 2)];

    float num = 0.f, den = 0.f;
    #pragma unroll 4
    for (int jj = 0; jj < 256; ++jj) {
        float dx = xi - sx[jj];
        float dy = yi - sy[jj];
        float dz = zi - sz[jj];
        float d2 = fmaf(dx, dx, fmaf(dy, dy, fmaf(dz, dz, EPS)));
        float r  = sqrtf(d2);
        float ov = fmaxf(SIGMA - r, 0.f);
        float ov2 = ov * ov;
        float clash = ov2 * ov2;
        float pm = fmi * sm[jj];
        int gj = jt * 256 + jj;
        pm = (gj == i) ? 0.f : pm;   // remove diagonal
        num = fmaf(clash, pm, num);
        den += pm;
    }

    // block reduction: 4 waves
    __shared__ float red[4 * 2];
    const int wid = tid >> 6, lane = tid & 63;
    float rn = wave_reduce_sum(num);
    float rd = wave_reduce_sum(den);
    if (lane == 0) { red[wid*2 + 0] = rn; red[wid*2 + 1] = rd; }
    __syncthreads();
    if (tid == 0) {
        float tn = red[0] + red[2] + red[4] + red[6];
        float td = red[1] + red[3] + red[5] + red[7];
        atomicAdd(ws + 0, tn);
        atomicAdd(ws + 1, td);
    }
}

// ---------------- H-bond term ----------------
// grid: (jt=2, it=2, b=8), block 256. dist(Nc_i, Oc_j), gaussian at 2.9,
// |i-j|>2 sequence-range mask.
__global__ void hb_kernel(const float* __restrict__ coords,
                          const float* __restrict__ mask,
                          float* __restrict__ ws) {
    const int b  = blockIdx.z;
    const int it = blockIdx.y;
    const int jt = blockIdx.x;
    const int tid = threadIdx.x;

    __shared__ float sx[256], sy[256], sz[256], sm[256];
    const float* cb = coords + (size_t)b * S * A * 3;

    const int j = jt * 256 + tid;
    // Oc = atom 3
    sx[tid] = cb[(j*4 + 3)*3 + 0];
    sy[tid] = cb[(j*4 + 3)*3 + 1];
    sz[tid] = cb[(j*4 + 3)*3 + 2];
    sm[tid] = mask[b*S + j];
    __syncthreads();

    const int i = it * 256 + tid;
    // Nc = atom 0
    const float xi = cb[(i*4 + 0)*3 + 0];
    const float yi = cb[(i*4 + 0)*3 + 1];
    const float zi = cb[(i*4 + 0)*3 + 2];
    const float mi = mask[b*S + i];

    float acc = 0.f;
    #pragma unroll 4
    for (int jj = 0; jj < 256; ++jj) {
        int gj = jt * 256 + jj;
        float dx = xi - sx[jj];
        float dy = yi - sy[jj];
        float dz = zi - sz[jj];
        float d2 = fmaf(dx, dx, fmaf(dy, dy, dz*dz));
        float dist = sqrtf(d2);           // NOTE: no EPS here (matches reference)
        float t = dist - HB_R0;
        float e = __expf(HB_COEF * t * t);
        int dd = i - gj; if (dd < 0) dd = -dd;
        float pm = (dd > 2) ? (mi * sm[jj]) : 0.f;
        acc = fmaf(e, pm, acc);
    }

    __shared__ float red[4];
    const int wid = tid >> 6, lane = tid & 63;
    float r = wave_reduce_sum(acc);
    if (lane == 0) red[wid] = r;
    __syncthreads();
    if (tid == 0) atomicAdd(ws + 2, red[0] + red[1] + red[2] + red[3]);
}

// ---------------- motor smoothness + Rg moments + mask sums ----------------
// grid: 8 (one block per batch), block 256.
__global__ void aux_kernel(const float* __restrict__ coords,
                           const float* __restrict__ motors,
                           const float* __restrict__ mask,
                           float* __restrict__ ws) {
    const int b = blockIdx.x;
    const int tid = threadIdx.x;

    float s1x = 0.f, s1y = 0.f, s1z = 0.f, s2 = 0.f, M = 0.f;
    float mnum = 0.f, mden = 0.f;

    for (int s = tid; s < S; s += 256) {
        float m = mask[b*S + s];
        const float* ca = coords + ((size_t)(b*S + s)*4 + 1)*3;  // atom 1
        float x = ca[0], y = ca[1], z = ca[2];
        s1x = fmaf(x, m, s1x);
        s1y = fmaf(y, m, s1y);
        s1z = fmaf(z, m, s1z);
        s2  = fmaf(fmaf(x,x,fmaf(y,y,z*z)), m, s2);
        M  += m;
        if (s < S - 1) {
            float mm = m * mask[b*S + s + 1];
            const float* m0 = motors + ((size_t)b*S + s)*8;
            float d = 0.f;
            #pragma unroll
            for (int k = 0; k < 8; ++k) {
                float df = m0[8 + k] - m0[k];
                d = fmaf(df, df, d);
            }
            mnum = fmaf(d, mm, mnum);
            mden += mm;
        }
    }

    __shared__ float red[4 * 7];
    const int wid = tid >> 6, lane = tid & 63;
    float vals[7] = {s1x, s1y, s1z, s2, M, mnum, mden};
    #pragma unroll
    for (int k = 0; k < 7; ++k) {
        float r = wave_reduce_sum(vals[k]);
        if (lane == 0) red[wid*7 + k] = r;
    }
    __syncthreads();
    if (tid == 0) {
        float t[7];
        #pragma unroll
        for (int k = 0; k < 7; ++k)
            t[k] = red[k] + red[7 + k] + red[14 + k] + red[21 + k];
        float* pb = ws + 8 + b*8;
        pb[0] = t[0]; pb[1] = t[1]; pb[2] = t[2]; pb[3] = t[3]; pb[4] = t[4];
        atomicAdd(ws + 3, t[4]);  // global mask sum
        atomicAdd(ws + 4, t[5]);  // motor numerator
        atomicAdd(ws + 5, t[6]);  // motor denominator
    }
}

// ---------------- final combine ----------------
__global__ void final_kernel(const float* __restrict__ ws, float* __restrict__ out) {
    if (threadIdx.x == 0 && blockIdx.x == 0) {
        float lj    = ws[0] / (ws[1] + EPS);
        float hb    = -ws[2] / (ws[3] + EPS);
        float motor = ws[4] / (ws[5] + EPS);
        float rg = 0.f;
        #pragma unroll
        for (int b = 0; b < B; ++b) {
            const float* p = ws + 8 + b*8;
            float Me = p[4] + EPS;
            float mx = p[0] / Me, my = p[1] / Me, mz = p[2] / Me;
            // sum m*|ca - mean|^2 = S2 - 2 mean.S1 + |mean|^2 * M
            float d2sum = p[3] - 2.f*(mx*p[0] + my*p[1] + mz*p[2])
                        + (mx*mx + my*my + mz*mz) * p[4];
            rg += d2sum / Me;
        }
        rg *= (1.f / (float)B);
        out[0] = lj + 0.5f*hb + 0.1f*motor + 0.05f*rg;
    }
}

extern "C" void kernel_launch(void* const* d_in, const int* in_sizes, int n_in,
                              void* d_out, int out_size, void* d_ws, size_t ws_size,
                              hipStream_t stream) {
    const float* coords = (const float*)d_in[0];
    const float* motors = (const float*)d_in[1];
    const float* mask   = (const float*)d_in[2];
    float* ws  = (float*)d_ws;
    float* out = (float*)d_out;

    // zero the accumulators (ws is poisoned 0xAA before every timed launch)
    hipMemsetAsync(ws, 0, 512, stream);

    dim3 glj(8, 8, 8);   // (jt, it, b)
    lj_kernel<<<glj, 256, 0, stream>>>(coords, mask, ws);

    dim3 ghb(2, 2, 8);   // (jt, it, b)
    hb_kernel<<<ghb, 256, 0, stream>>>(coords, mask, ws);

    aux_kernel<<<8, 256, 0, stream>>>(coords, motors, mask, ws);

    final_kernel<<<1, 64, 0, stream>>>(ws, out);
}

// Round 2
// 68.506 us; speedup vs baseline: 1.9175x; 1.9175x over previous
//
#include <hip/hip_runtime.h>
#include <hip/hip_bf16.h>
#include <math.h>

// Problem constants (from reference)
#define B 8
#define S 512
#define A 4
#define N (S*A)          // 2048 points per batch for the LJ term
#define SIGMA 3.0f
#define HB_R0 2.9f
#define HB_COEF (-12.5f) // -0.5 / 0.2^2
#define EPS 1e-6f

// Block roles in the fused kernel (1D grid):
//   [0, NLJ)            LJ tile-pair halves: 8 batches x 36 (it<=jt) x 2 j-halves
//   [NLJ, NLJ+NHB)      HB tiles: 8 batches x 2 i-tiles(256) x 4 j-quarters(128)
//   [NLJ+NHB, +NAUX)    per-batch aux moments (Rg, motor, mask sums)
#define NLJ 576
#define NHB 64
#define NAUX 8
#define NBLOCKS (NLJ + NHB + NAUX)

// ws layout (floats) — every slot we read is written by exactly one block,
// so no zero-init and no atomics are needed:
//   [0, 576)        LJ partial numerators
//   [576, 640)      HB partial numerators
//   [640 + b*8 + k) aux per batch: S1x,S1y,S1z,S2,M,Sm2,motor_num,motor_den
#define WS_LJ  0
#define WS_HB  576
#define WS_AUX 640

__device__ __forceinline__ float wave_reduce_sum(float v) {
    #pragma unroll
    for (int off = 32; off > 0; off >>= 1) v += __shfl_down(v, off, 64);
    return v;
}

__global__ __launch_bounds__(256) void physics_main(
        const float* __restrict__ coords,
        const float* __restrict__ motors,
        const float* __restrict__ mask,
        float* __restrict__ ws) {
    const int bid = blockIdx.x;
    const int tid = threadIdx.x;

    __shared__ float4 sj[128];     // staged j-points: (x,y,z,mask)
    __shared__ float  redbuf[32];  // 4 waves x up to 8 values

    const int wid = tid >> 6, lane = tid & 63;

    if (bid < NLJ) {
        // ---------------- LJ clash (symmetric tiles) ----------------
        const int b    = bid / 72;
        const int r    = bid % 72;
        const int p    = r >> 1;        // tile-pair index in upper triangle
        const int half = r & 1;         // which 128-wide j half
        int it = 0, pp = p;
        while (pp >= 8 - it) { pp -= 8 - it; ++it; }
        const int jt = it + pp;         // it <= jt

        const float* cb = coords + (size_t)b * N * 3;
        const float* mb = mask + b * S;
        const int jlo = jt * 256 + half * 128;

        if (tid < 128) {
            const int j = jlo + tid;
            sj[tid] = make_float4(cb[j*3+0], cb[j*3+1], cb[j*3+2], mb[j >> 2]);
        }
        __syncthreads();

        const int i = it * 256 + tid;
        const float xi = cb[i*3+0], yi = cb[i*3+1], zi = cb[i*3+2];
        const float fmi = mb[i >> 2];

        float acc = 0.f;
        #pragma unroll 8
        for (int jj = 0; jj < 128; ++jj) {
            const float4 q = sj[jj];
            const float dx = xi - q.x;
            const float dy = yi - q.y;
            const float dz = zi - q.z;
            const float d2 = fmaf(dx, dx, fmaf(dy, dy, fmaf(dz, dz, EPS)));
            const float rr = __builtin_amdgcn_sqrtf(d2);
            const float ov = fmaxf(SIGMA - rr, 0.f);
            const float ov2 = ov * ov;
            acc = fmaf(ov2 * ov2, q.w, acc);
        }
        // remove i==j (only possible in diagonal tiles); bit-identical expr
        if (it == jt && i >= jlo && i < jlo + 128) {
            const float ovd = SIGMA - __builtin_amdgcn_sqrtf(EPS);
            const float o2 = ovd * ovd;
            acc -= fmi * (o2 * o2);
        }
        float v = fmi * acc;
        if (it != jt) v *= 2.f;          // count (j,i) pairs too

        v = wave_reduce_sum(v);
        if (lane == 0) redbuf[wid] = v;
        __syncthreads();
        if (tid == 0) ws[WS_LJ + bid] = redbuf[0] + redbuf[1] + redbuf[2] + redbuf[3];

    } else if (bid < NLJ + NHB) {
        // ---------------- H-bond term ----------------
        const int idx = bid - NLJ;      // [0, 64)
        const int b  = idx >> 3;
        const int rr_ = idx & 7;
        const int it = rr_ >> 2;        // 0..1 (i tiles of 256)
        const int jh = rr_ & 3;         // 0..3 (j quarters of 128)

        const float* cb = coords + (size_t)b * S * A * 3;
        const float* mb = mask + b * S;
        const int jlo = jh * 128;

        if (tid < 128) {
            const int j = jlo + tid;    // Oc = atom 3
            sj[tid] = make_float4(cb[(j*4+3)*3+0], cb[(j*4+3)*3+1],
                                  cb[(j*4+3)*3+2], mb[j]);
        }
        __syncthreads();

        const int i = it * 256 + tid;   // Nc = atom 0
        const float xi = cb[(i*4+0)*3+0];
        const float yi = cb[(i*4+0)*3+1];
        const float zi = cb[(i*4+0)*3+2];
        const float mi = mb[i];

        float acc = 0.f;
        #pragma unroll 8
        for (int jj = 0; jj < 128; ++jj) {
            const float4 q = sj[jj];
            const float dx = xi - q.x;
            const float dy = yi - q.y;
            const float dz = zi - q.z;
            const float d2 = fmaf(dx, dx, fmaf(dy, dy, dz * dz)); // no EPS (ref)
            const float dist = __builtin_amdgcn_sqrtf(d2);
            const float t = dist - HB_R0;
            const float e = __expf(HB_COEF * (t * t));
            acc = fmaf(e, q.w, acc);
        }
        // subtract the |i-j| <= 2 band (range_mask==0 there); bit-identical expr
        #pragma unroll
        for (int dj = -2; dj <= 2; ++dj) {
            const int j = i + dj;
            if (j >= jlo && j < jlo + 128) {
                const float4 q = sj[j - jlo];
                const float dx = xi - q.x;
                const float dy = yi - q.y;
                const float dz = zi - q.z;
                const float d2 = fmaf(dx, dx, fmaf(dy, dy, dz * dz));
                const float dist = __builtin_amdgcn_sqrtf(d2);
                const float t = dist - HB_R0;
                const float e = __expf(HB_COEF * (t * t));
                acc -= e * q.w;
            }
        }
        float v = mi * acc;
        v = wave_reduce_sum(v);
        if (lane == 0) redbuf[wid] = v;
        __syncthreads();
        if (tid == 0) ws[WS_HB + idx] = redbuf[0] + redbuf[1] + redbuf[2] + redbuf[3];

    } else {
        // ---------------- aux: Rg moments, motor smoothness, mask sums ----------------
        const int b = bid - NLJ - NHB;
        const float* cb = coords + (size_t)b * S * A * 3;
        const float* mb = mask + b * S;

        float s1x = 0.f, s1y = 0.f, s1z = 0.f, s2 = 0.f, M = 0.f, Sm2 = 0.f;
        float mn = 0.f, md = 0.f;

        for (int s = tid; s < S; s += 256) {
            const float m = mb[s];
            const float* ca = cb + ((size_t)(s*4 + 1)) * 3;   // atom 1
            const float x = ca[0], y = ca[1], z = ca[2];
            s1x = fmaf(x, m, s1x);
            s1y = fmaf(y, m, s1y);
            s1z = fmaf(z, m, s1z);
            s2  = fmaf(fmaf(x, x, fmaf(y, y, z * z)), m, s2);
            M   += m;
            Sm2 = fmaf(m, m, Sm2);
            if (s < S - 1) {
                const float mm = m * mb[s + 1];
                const float4* m4 = (const float4*)(motors + ((size_t)b * S + s) * 8);
                const float4 a0 = m4[0], a1 = m4[1], b0 = m4[2], b1 = m4[3];
                float d = 0.f;
                float df;
                df = b0.x - a0.x; d = fmaf(df, df, d);
                df = b0.y - a0.y; d = fmaf(df, df, d);
                df = b0.z - a0.z; d = fmaf(df, df, d);
                df = b0.w - a0.w; d = fmaf(df, df, d);
                df = b1.x - a1.x; d = fmaf(df, df, d);
                df = b1.y - a1.y; d = fmaf(df, df, d);
                df = b1.z - a1.z; d = fmaf(df, df, d);
                df = b1.w - a1.w; d = fmaf(df, df, d);
                mn = fmaf(d, mm, mn);
                md += mm;
            }
        }

        float vals[8] = {s1x, s1y, s1z, s2, M, Sm2, mn, md};
        #pragma unroll
        for (int k = 0; k < 8; ++k) {
            float v = wave_reduce_sum(vals[k]);
            if (lane == 0) redbuf[wid * 8 + k] = v;
        }
        __syncthreads();
        if (tid < 8) {
            const float t = redbuf[tid] + redbuf[8 + tid] + redbuf[16 + tid] + redbuf[24 + tid];
            ws[WS_AUX + b * 8 + tid] = t;
        }
    }
}

__global__ __launch_bounds__(256) void physics_final(
        const float* __restrict__ ws, float* __restrict__ out) {
    const int tid = threadIdx.x;
    const int wid = tid >> 6, lane = tid & 63;
    __shared__ float redbuf[8];

    float lj = 0.f;
    for (int i = tid; i < NLJ; i += 256) lj += ws[WS_LJ + i];
    float hb = (tid < NHB) ? ws[WS_HB + tid] : 0.f;

    lj = wave_reduce_sum(lj);
    hb = wave_reduce_sum(hb);
    if (lane == 0) { redbuf[wid * 2 + 0] = lj; redbuf[wid * 2 + 1] = hb; }
    __syncthreads();

    if (tid == 0) {
        const float lj_num = redbuf[0] + redbuf[2] + redbuf[4] + redbuf[6];
        const float hb_num = redbuf[1] + redbuf[3] + redbuf[5] + redbuf[7];

        float lj_den = 0.f, masksum = 0.f, mnum = 0.f, mden = 0.f, rg = 0.f;
        #pragma unroll
        for (int b = 0; b < B; ++b) {
            const float* p = ws + WS_AUX + b * 8;
            const float M = p[4], Sm2 = p[5];
            lj_den  += 16.f * M * M - 4.f * Sm2;   // sum pair_mask, analytic
            masksum += M;
            mnum    += p[6];
            mden    += p[7];
            const float Me = M + EPS;
            const float mx = p[0] / Me, my = p[1] / Me, mz = p[2] / Me;
            // sum m*|ca-mean|^2 = S2 - 2 mean.S1 + |mean|^2 * M
            const float d2sum = p[3] - 2.f * (mx * p[0] + my * p[1] + mz * p[2])
                              + (mx * mx + my * my + mz * mz) * M;
            rg += d2sum / Me;
        }
        rg *= (1.f / (float)B);

        const float ljv   = lj_num / (lj_den + EPS);
        const float hbv   = -hb_num / (masksum + EPS);
        const float motor = mnum / (mden + EPS);
        out[0] = ljv + 0.5f * hbv + 0.1f * motor + 0.05f * rg;
    }
}

extern "C" void kernel_launch(void* const* d_in, const int* in_sizes, int n_in,
                              void* d_out, int out_size, void* d_ws, size_t ws_size,
                              hipStream_t stream) {
    const float* coords = (const float*)d_in[0];
    const float* motors = (const float*)d_in[1];
    const float* mask   = (const float*)d_in[2];
    float* ws  = (float*)d_ws;
    float* out = (float*)d_out;

    physics_main<<<NBLOCKS, 256, 0, stream>>>(coords, motors, mask, ws);
    physics_final<<<1, 256, 0, stream>>>(ws, out);
}